// Round 1
// baseline (353.259 us; speedup 1.0000x reference)
//
#include <hip/hip_runtime.h>
#include <hip/hip_bf16.h>

// ---------------------------------------------------------------------------
// 2-layer GCN: out = GCN2( relu(GCN1(X)) ), GCN(x) = Dinv (A+I) Dinv (x W) + b
// Strategy:
//   1. deg[dst]++ (int atomics) -> dinv = rsqrt(deg+1)
//   2. CSR-by-dst build: scan(deg) -> rowstart, scatter src ids (1 int atomic/edge)
//   3. GEMM H = X @ W (fp32 register-tiled; no fp32 MFMA on CDNA4)
//   4. SpMM gather: wave-per-node, acc += H[src] * dinv[src]*dinv[dst], + self,
//      + bias (+relu), written once, coalesced. No float atomics anywhere.
// ---------------------------------------------------------------------------

#define WS_OFF_DEG       (size_t)0
#define WS_OFF_ROWSTART  (size_t)200192
#define WS_OFF_CURSOR    (size_t)400384
#define WS_OFF_DINV      (size_t)600576
#define WS_OFF_BLOCKSUM  (size_t)800768
#define WS_OFF_FLAG      (size_t)801792
#define WS_OFF_CSR       (size_t)802048
#define WS_OFF_BUFA      (size_t)4002304    // N*128 floats (H1, later H2)
#define WS_OFF_BUFB      (size_t)29602304   // N*128 floats (X1)

// --- edge dtype detection: flag=1 if edges are int64 (high words all zero) ---
__global__ void k_detect(const int* __restrict__ e32, int* __restrict__ flag) {
    __shared__ int any;
    if (threadIdx.x == 0) any = 0;
    __syncthreads();
    int v = 0;
    for (int i = threadIdx.x; i < 4096; i += blockDim.x) v |= e32[2 * i + 1];
    if (v) atomicOr(&any, 1);
    __syncthreads();
    if (threadIdx.x == 0) *flag = (any == 0) ? 1 : 0;
}

__global__ void k_zero_int(int* __restrict__ p, int n) {
    int i = blockIdx.x * 256 + threadIdx.x;
    if (i < n) p[i] = 0;
}

__global__ void k_count(const int* __restrict__ e32, int E,
                        const int* __restrict__ flag, int* __restrict__ deg) {
    int e = blockIdx.x * 256 + threadIdx.x;
    if (e >= E) return;
    int f = *flag;                 // uniform
    int st = f ? 4 : 2, ho = f ? 2 : 1;
    int dst = e32[e * st + ho];
    atomicAdd(&deg[dst], 1);
}

__global__ void k_dinv(const int* __restrict__ deg, int n, float* __restrict__ dinv) {
    int i = blockIdx.x * 256 + threadIdx.x;
    if (i < n) dinv[i] = rsqrtf((float)deg[i] + 1.0f);
}

// --- 3-kernel exclusive scan over deg[n] (n <= 256*256) ---
__global__ void k_scan1(const int* __restrict__ deg, int n,
                        int* __restrict__ rowstart, int* __restrict__ blocksum) {
    __shared__ int sh[256];
    int t = threadIdx.x, i = blockIdx.x * 256 + t;
    int v = (i < n) ? deg[i] : 0;
    sh[t] = v;
    __syncthreads();
    for (int off = 1; off < 256; off <<= 1) {
        int add = (t >= off) ? sh[t - off] : 0;
        __syncthreads();
        sh[t] += add;
        __syncthreads();
    }
    if (i < n) rowstart[i] = sh[t] - v;          // block-local exclusive
    if (t == 255) blocksum[blockIdx.x] = sh[255];
}

__global__ void k_scan2(int* __restrict__ blocksum, int nb) {
    __shared__ int sh[256];
    int t = threadIdx.x;
    int v = (t < nb) ? blocksum[t] : 0;
    sh[t] = v;
    __syncthreads();
    for (int off = 1; off < 256; off <<= 1) {
        int add = (t >= off) ? sh[t - off] : 0;
        __syncthreads();
        sh[t] += add;
        __syncthreads();
    }
    if (t < nb) blocksum[t] = sh[t] - v;         // exclusive block offsets
}

__global__ void k_scan3(int* __restrict__ rowstart, int n,
                        const int* __restrict__ blocksum,
                        int* __restrict__ cursor, int E) {
    int i = blockIdx.x * 256 + threadIdx.x;
    if (i < n) {
        int r = rowstart[i] + blocksum[blockIdx.x];
        rowstart[i] = r;
        cursor[i] = r;
    }
    if (i == 0) rowstart[n] = E;
}

__global__ void k_fill(const int* __restrict__ e32, int E,
                       const int* __restrict__ flag,
                       int* __restrict__ cursor, int* __restrict__ csr) {
    int e = blockIdx.x * 256 + threadIdx.x;
    if (e >= E) return;
    int f = *flag;
    int st = f ? 4 : 2, ho = f ? 2 : 1;
    int src = e32[e * st];
    int dst = e32[e * st + ho];
    int pos = atomicAdd(&cursor[dst], 1);
    csr[pos] = src;
}

// --- GEMM1: [n x 128] @ [128 x 128], block tile 128x128, thread micro 8x8 ---
__global__ __launch_bounds__(256) void k_gemm1(const float* __restrict__ X,
                                               const float* __restrict__ W,
                                               float* __restrict__ out, int n) {
    __shared__ float XsT[32][132];   // [k][row], padded
    __shared__ float Ws[32][128];    // [k][col]
    const int t = threadIdx.x;
    const int tx = t & 15, ty = t >> 4;
    const int row0 = blockIdx.x * 128;
    float acc[8][8] = {};
    for (int kt = 0; kt < 128; kt += 32) {
        for (int i = t; i < 128 * 8; i += 256) {     // X tile: 128 rows x 8 float4
            int r = i >> 3, c4 = i & 7;
            int gr = row0 + r;
            float4 v = make_float4(0.f, 0.f, 0.f, 0.f);
            if (gr < n) v = reinterpret_cast<const float4*>(X + (size_t)gr * 128 + kt)[c4];
            XsT[c4 * 4 + 0][r] = v.x;
            XsT[c4 * 4 + 1][r] = v.y;
            XsT[c4 * 4 + 2][r] = v.z;
            XsT[c4 * 4 + 3][r] = v.w;
        }
        for (int i = t; i < 32 * 32; i += 256) {     // W tile: 32 rows x 32 float4
            int kk = i >> 5, c4 = i & 31;
            reinterpret_cast<float4*>(&Ws[kk][0])[c4] =
                reinterpret_cast<const float4*>(W + (size_t)(kt + kk) * 128)[c4];
        }
        __syncthreads();
#pragma unroll
        for (int kk = 0; kk < 32; ++kk) {
            float a[8], b[8];
#pragma unroll
            for (int i = 0; i < 8; i++) a[i] = XsT[kk][ty * 8 + i];
#pragma unroll
            for (int j = 0; j < 8; j++) b[j] = Ws[kk][tx * 8 + j];
#pragma unroll
            for (int i = 0; i < 8; i++)
#pragma unroll
                for (int j = 0; j < 8; j++) acc[i][j] += a[i] * b[j];
        }
        __syncthreads();
    }
    for (int i = 0; i < 8; i++) {
        int gr = row0 + ty * 8 + i;
        if (gr < n) {
            float4* o = reinterpret_cast<float4*>(out + (size_t)gr * 128 + tx * 8);
            o[0] = make_float4(acc[i][0], acc[i][1], acc[i][2], acc[i][3]);
            o[1] = make_float4(acc[i][4], acc[i][5], acc[i][6], acc[i][7]);
        }
    }
}

// --- GEMM2: [n x 128] @ [128 x 64], block tile 256x64, thread micro 8x8 ---
__global__ __launch_bounds__(256) void k_gemm2(const float* __restrict__ X,
                                               const float* __restrict__ W,
                                               float* __restrict__ out, int n) {
    __shared__ float XsT[32][260];   // [k][row], padded
    __shared__ float Ws[32][64];     // [k][col]
    const int t = threadIdx.x;
    const int tx = t & 7, ty = t >> 3;
    const int row0 = blockIdx.x * 256;
    float acc[8][8] = {};
    for (int kt = 0; kt < 128; kt += 32) {
        for (int i = t; i < 256 * 8; i += 256) {     // X tile: 256 rows x 8 float4
            int r = i >> 3, c4 = i & 7;
            int gr = row0 + r;
            float4 v = make_float4(0.f, 0.f, 0.f, 0.f);
            if (gr < n) v = reinterpret_cast<const float4*>(X + (size_t)gr * 128 + kt)[c4];
            XsT[c4 * 4 + 0][r] = v.x;
            XsT[c4 * 4 + 1][r] = v.y;
            XsT[c4 * 4 + 2][r] = v.z;
            XsT[c4 * 4 + 3][r] = v.w;
        }
        for (int i = t; i < 32 * 16; i += 256) {     // W tile: 32 rows x 16 float4
            int kk = i >> 4, c4 = i & 15;
            reinterpret_cast<float4*>(&Ws[kk][0])[c4] =
                reinterpret_cast<const float4*>(W + (size_t)(kt + kk) * 64)[c4];
        }
        __syncthreads();
#pragma unroll
        for (int kk = 0; kk < 32; ++kk) {
            float a[8], b[8];
#pragma unroll
            for (int i = 0; i < 8; i++) a[i] = XsT[kk][ty * 8 + i];
#pragma unroll
            for (int j = 0; j < 8; j++) b[j] = Ws[kk][tx * 8 + j];
#pragma unroll
            for (int i = 0; i < 8; i++)
#pragma unroll
                for (int j = 0; j < 8; j++) acc[i][j] += a[i] * b[j];
        }
        __syncthreads();
    }
    for (int i = 0; i < 8; i++) {
        int gr = row0 + ty * 8 + i;
        if (gr < n) {
            float4* o = reinterpret_cast<float4*>(out + (size_t)gr * 64 + tx * 8);
            o[0] = make_float4(acc[i][0], acc[i][1], acc[i][2], acc[i][3]);
            o[1] = make_float4(acc[i][4], acc[i][5], acc[i][6], acc[i][7]);
        }
    }
}

// --- SpMM, F=128: one wave per node, lane handles a float2 (2 features) ---
__global__ __launch_bounds__(256) void k_spmm128(
        const float* __restrict__ H, const int* __restrict__ rowstart,
        const int* __restrict__ csr, const float* __restrict__ dinv,
        const float* __restrict__ bias, float* __restrict__ out, int n) {
    int node = blockIdx.x * 4 + (threadIdx.x >> 6);
    if (node >= n) return;
    int lane = threadIdx.x & 63;
    const float2* H2 = reinterpret_cast<const float2*>(H);
    float di = dinv[node];
    float2 v = H2[(size_t)node * 64 + lane];
    float selfw = di * di;
    float2 acc = make_float2(v.x * selfw, v.y * selfw);
    int s0 = rowstart[node], s1 = rowstart[node + 1];
    for (int j = s0; j < s1; ++j) {
        int src = csr[j];
        float w = dinv[src] * di;
        float2 u = H2[(size_t)src * 64 + lane];
        acc.x += u.x * w;
        acc.y += u.y * w;
    }
    float2 b = reinterpret_cast<const float2*>(bias)[lane];
    acc.x = fmaxf(acc.x + b.x, 0.f);
    acc.y = fmaxf(acc.y + b.y, 0.f);
    reinterpret_cast<float2*>(out)[(size_t)node * 64 + lane] = acc;
}

// --- SpMM, F=64: one wave per node, lane handles 1 feature; no relu ---
__global__ __launch_bounds__(256) void k_spmm64(
        const float* __restrict__ H, const int* __restrict__ rowstart,
        const int* __restrict__ csr, const float* __restrict__ dinv,
        const float* __restrict__ bias, float* __restrict__ out, int n) {
    int node = blockIdx.x * 4 + (threadIdx.x >> 6);
    if (node >= n) return;
    int lane = threadIdx.x & 63;
    float di = dinv[node];
    float acc = H[(size_t)node * 64 + lane] * (di * di);
    int s0 = rowstart[node], s1 = rowstart[node + 1];
    for (int j = s0; j < s1; ++j) {
        int src = csr[j];
        acc += H[(size_t)src * 64 + lane] * (dinv[src] * di);
    }
    out[(size_t)node * 64 + lane] = acc + bias[lane];
}

extern "C" void kernel_launch(void* const* d_in, const int* in_sizes, int n_in,
                              void* d_out, int out_size, void* d_ws, size_t ws_size,
                              hipStream_t stream) {
    const float* X  = (const float*)d_in[0];
    const int*   e32 = (const int*)d_in[1];
    const float* W1 = (const float*)d_in[2];
    const float* b1 = (const float*)d_in[3];
    const float* W2 = (const float*)d_in[4];
    const float* b2 = (const float*)d_in[5];
    float* out = (float*)d_out;

    const int n = in_sizes[0] / 128;
    const int E = in_sizes[1] / 2;

    char* ws = (char*)d_ws;
    int*   deg      = (int*)(ws + WS_OFF_DEG);
    int*   rowstart = (int*)(ws + WS_OFF_ROWSTART);
    int*   cursor   = (int*)(ws + WS_OFF_CURSOR);
    float* dinv     = (float*)(ws + WS_OFF_DINV);
    int*   blocksum = (int*)(ws + WS_OFF_BLOCKSUM);
    int*   flag     = (int*)(ws + WS_OFF_FLAG);
    int*   csr      = (int*)(ws + WS_OFF_CSR);
    float* bufA     = (float*)(ws + WS_OFF_BUFA);   // H1 [n][128], later H2 [n][64]
    float* bufB     = (float*)(ws + WS_OFF_BUFB);   // X1 [n][128]

    const int NB = (n + 255) / 256;

    k_detect<<<1, 256, 0, stream>>>(e32, flag);
    k_zero_int<<<NB, 256, 0, stream>>>(deg, n);
    k_count<<<(E + 255) / 256, 256, 0, stream>>>(e32, E, flag, deg);
    k_dinv<<<NB, 256, 0, stream>>>(deg, n, dinv);
    k_scan1<<<NB, 256, 0, stream>>>(deg, n, rowstart, blocksum);
    k_scan2<<<1, 256, 0, stream>>>(blocksum, NB);
    k_scan3<<<NB, 256, 0, stream>>>(rowstart, n, blocksum, cursor, E);
    k_fill<<<(E + 255) / 256, 256, 0, stream>>>(e32, E, flag, cursor, csr);

    k_gemm1<<<(n + 127) / 128, 256, 0, stream>>>(X, W1, bufA, n);
    k_spmm128<<<(n + 3) / 4, 256, 0, stream>>>(bufA, rowstart, csr, dinv, b1, bufB, n);
    k_gemm2<<<(n + 255) / 256, 256, 0, stream>>>(bufB, W2, bufA, n);
    k_spmm64<<<(n + 3) / 4, 256, 0, stream>>>(bufA, rowstart, csr, dinv, b2, out, n);
}

// Round 2
// 251.144 us; speedup vs baseline: 1.4066x; 1.4066x over previous
//
#include <hip/hip_runtime.h>
#include <hip/hip_bf16.h>

// ---------------------------------------------------------------------------
// 2-layer GCN: out = GCN2( relu(GCN1(X)) ), GCN(x) = Dinv (A+I) Dinv (x W) + b
//   1. deg[dst]++ (int atomics) -> dinv = rsqrt(deg+1)
//   2. CSR-by-dst build: scan(deg) -> rowstart, scatter src ids
//   3. GEMM Hs = (X @ W) * dinv[row]   (dinv folded into epilogue)
//   4. SpMM gather: wave-per-node, acc = sum Hs[src] (8-deep unrolled MLP),
//      out = dinv[node]*acc + b (+relu). No float atomics anywhere.
// ---------------------------------------------------------------------------

#define WS_OFF_DEG       (size_t)0
#define WS_OFF_ROWSTART  (size_t)200192
#define WS_OFF_CURSOR    (size_t)400384
#define WS_OFF_DINV      (size_t)600576
#define WS_OFF_BLOCKSUM  (size_t)800768
#define WS_OFF_FLAG      (size_t)801792
#define WS_OFF_CSR       (size_t)802048
#define WS_OFF_BUFA      (size_t)4002304    // N*128 floats (Hs1, later Hs2)
#define WS_OFF_BUFB      (size_t)29602304   // N*128 floats (X1)

// --- edge dtype detection: flag=1 if edges are int64 (high words all zero) ---
__global__ void k_detect(const int* __restrict__ e32, int* __restrict__ flag) {
    __shared__ int any;
    if (threadIdx.x == 0) any = 0;
    __syncthreads();
    int v = 0;
    for (int i = threadIdx.x; i < 4096; i += blockDim.x) v |= e32[2 * i + 1];
    if (v) atomicOr(&any, 1);
    __syncthreads();
    if (threadIdx.x == 0) *flag = (any == 0) ? 1 : 0;
}

__global__ void k_zero_int(int* __restrict__ p, int n) {
    int i = blockIdx.x * 256 + threadIdx.x;
    if (i < n) p[i] = 0;
}

__global__ void k_count(const int* __restrict__ e32, int E,
                        const int* __restrict__ flag, int* __restrict__ deg) {
    int e = blockIdx.x * 256 + threadIdx.x;
    if (e >= E) return;
    int f = *flag;                 // uniform
    int st = f ? 4 : 2, ho = f ? 2 : 1;
    int dst = e32[e * st + ho];
    atomicAdd(&deg[dst], 1);
}

__global__ void k_dinv(const int* __restrict__ deg, int n, float* __restrict__ dinv) {
    int i = blockIdx.x * 256 + threadIdx.x;
    if (i < n) dinv[i] = rsqrtf((float)deg[i] + 1.0f);
}

// --- 3-kernel exclusive scan over deg[n] (n <= 256*256) ---
__global__ void k_scan1(const int* __restrict__ deg, int n,
                        int* __restrict__ rowstart, int* __restrict__ blocksum) {
    __shared__ int sh[256];
    int t = threadIdx.x, i = blockIdx.x * 256 + t;
    int v = (i < n) ? deg[i] : 0;
    sh[t] = v;
    __syncthreads();
    for (int off = 1; off < 256; off <<= 1) {
        int add = (t >= off) ? sh[t - off] : 0;
        __syncthreads();
        sh[t] += add;
        __syncthreads();
    }
    if (i < n) rowstart[i] = sh[t] - v;          // block-local exclusive
    if (t == 255) blocksum[blockIdx.x] = sh[255];
}

__global__ void k_scan2(int* __restrict__ blocksum, int nb) {
    __shared__ int sh[256];
    int t = threadIdx.x;
    int v = (t < nb) ? blocksum[t] : 0;
    sh[t] = v;
    __syncthreads();
    for (int off = 1; off < 256; off <<= 1) {
        int add = (t >= off) ? sh[t - off] : 0;
        __syncthreads();
        sh[t] += add;
        __syncthreads();
    }
    if (t < nb) blocksum[t] = sh[t] - v;         // exclusive block offsets
}

__global__ void k_scan3(int* __restrict__ rowstart, int n,
                        const int* __restrict__ blocksum,
                        int* __restrict__ cursor, int E) {
    int i = blockIdx.x * 256 + threadIdx.x;
    if (i < n) {
        int r = rowstart[i] + blocksum[blockIdx.x];
        rowstart[i] = r;
        cursor[i] = r;
    }
    if (i == 0) rowstart[n] = E;
}

__global__ void k_fill(const int* __restrict__ e32, int E,
                       const int* __restrict__ flag,
                       int* __restrict__ cursor, int* __restrict__ csr) {
    int e = blockIdx.x * 256 + threadIdx.x;
    if (e >= E) return;
    int f = *flag;
    int st = f ? 4 : 2, ho = f ? 2 : 1;
    int src = e32[e * st];
    int dst = e32[e * st + ho];
    int pos = atomicAdd(&cursor[dst], 1);
    csr[pos] = src;
}

// --- GEMM1: [n x 128] @ [128 x 128], out scaled by dinv[row] -----------------
__global__ __launch_bounds__(256) void k_gemm1(const float* __restrict__ X,
                                               const float* __restrict__ W,
                                               const float* __restrict__ dinv,
                                               float* __restrict__ out, int n) {
    __shared__ float XsT[32][132];   // [k][row], padded
    __shared__ float Ws[32][128];    // [k][col]
    const int t = threadIdx.x;
    const int tx = t & 15, ty = t >> 4;
    const int row0 = blockIdx.x * 128;
    float acc[8][8] = {};
    for (int kt = 0; kt < 128; kt += 32) {
        for (int i = t; i < 128 * 8; i += 256) {     // X tile: 128 rows x 8 float4
            int r = i >> 3, c4 = i & 7;
            int gr = row0 + r;
            float4 v = make_float4(0.f, 0.f, 0.f, 0.f);
            if (gr < n) v = reinterpret_cast<const float4*>(X + (size_t)gr * 128 + kt)[c4];
            XsT[c4 * 4 + 0][r] = v.x;
            XsT[c4 * 4 + 1][r] = v.y;
            XsT[c4 * 4 + 2][r] = v.z;
            XsT[c4 * 4 + 3][r] = v.w;
        }
        for (int i = t; i < 32 * 32; i += 256) {     // W tile: 32 rows x 32 float4
            int kk = i >> 5, c4 = i & 31;
            reinterpret_cast<float4*>(&Ws[kk][0])[c4] =
                reinterpret_cast<const float4*>(W + (size_t)(kt + kk) * 128)[c4];
        }
        __syncthreads();
#pragma unroll
        for (int kk = 0; kk < 32; ++kk) {
            float a[8], b[8];
#pragma unroll
            for (int i = 0; i < 8; i++) a[i] = XsT[kk][ty * 8 + i];
#pragma unroll
            for (int j = 0; j < 8; j++) b[j] = Ws[kk][tx * 8 + j];
#pragma unroll
            for (int i = 0; i < 8; i++)
#pragma unroll
                for (int j = 0; j < 8; j++) acc[i][j] += a[i] * b[j];
        }
        __syncthreads();
    }
    for (int i = 0; i < 8; i++) {
        int gr = row0 + ty * 8 + i;
        if (gr < n) {
            float dv = dinv[gr];
            float4* o = reinterpret_cast<float4*>(out + (size_t)gr * 128 + tx * 8);
            o[0] = make_float4(acc[i][0] * dv, acc[i][1] * dv, acc[i][2] * dv, acc[i][3] * dv);
            o[1] = make_float4(acc[i][4] * dv, acc[i][5] * dv, acc[i][6] * dv, acc[i][7] * dv);
        }
    }
}

// --- GEMM2: [n x 128] @ [128 x 64], out scaled by dinv[row] ------------------
__global__ __launch_bounds__(256) void k_gemm2(const float* __restrict__ X,
                                               const float* __restrict__ W,
                                               const float* __restrict__ dinv,
                                               float* __restrict__ out, int n) {
    __shared__ float XsT[32][260];   // [k][row], padded
    __shared__ float Ws[32][64];     // [k][col]
    const int t = threadIdx.x;
    const int tx = t & 7, ty = t >> 3;
    const int row0 = blockIdx.x * 256;
    float acc[8][8] = {};
    for (int kt = 0; kt < 128; kt += 32) {
        for (int i = t; i < 256 * 8; i += 256) {     // X tile: 256 rows x 8 float4
            int r = i >> 3, c4 = i & 7;
            int gr = row0 + r;
            float4 v = make_float4(0.f, 0.f, 0.f, 0.f);
            if (gr < n) v = reinterpret_cast<const float4*>(X + (size_t)gr * 128 + kt)[c4];
            XsT[c4 * 4 + 0][r] = v.x;
            XsT[c4 * 4 + 1][r] = v.y;
            XsT[c4 * 4 + 2][r] = v.z;
            XsT[c4 * 4 + 3][r] = v.w;
        }
        for (int i = t; i < 32 * 16; i += 256) {     // W tile: 32 rows x 16 float4
            int kk = i >> 4, c4 = i & 15;
            reinterpret_cast<float4*>(&Ws[kk][0])[c4] =
                reinterpret_cast<const float4*>(W + (size_t)(kt + kk) * 64)[c4];
        }
        __syncthreads();
#pragma unroll
        for (int kk = 0; kk < 32; ++kk) {
            float a[8], b[8];
#pragma unroll
            for (int i = 0; i < 8; i++) a[i] = XsT[kk][ty * 8 + i];
#pragma unroll
            for (int j = 0; j < 8; j++) b[j] = Ws[kk][tx * 8 + j];
#pragma unroll
            for (int i = 0; i < 8; i++)
#pragma unroll
                for (int j = 0; j < 8; j++) acc[i][j] += a[i] * b[j];
        }
        __syncthreads();
    }
    for (int i = 0; i < 8; i++) {
        int gr = row0 + ty * 8 + i;
        if (gr < n) {
            float dv = dinv[gr];
            float4* o = reinterpret_cast<float4*>(out + (size_t)gr * 64 + tx * 8);
            o[0] = make_float4(acc[i][0] * dv, acc[i][1] * dv, acc[i][2] * dv, acc[i][3] * dv);
            o[1] = make_float4(acc[i][4] * dv, acc[i][5] * dv, acc[i][6] * dv, acc[i][7] * dv);
        }
    }
}

// --- SpMM, F=128: wave per node, lane = float2; 8-deep unrolled gather -------
__global__ __launch_bounds__(256) void k_spmm128(
        const float* __restrict__ Hs, const int* __restrict__ rowstart,
        const int* __restrict__ csr, const float* __restrict__ dinv,
        const float* __restrict__ bias, float* __restrict__ out, int n) {
    int node = blockIdx.x * 4 + (threadIdx.x >> 6);
    if (node >= n) return;
    int lane = threadIdx.x & 63;
    const float2* H2 = reinterpret_cast<const float2*>(Hs);
    float di = dinv[node];
    float2 acc = H2[(size_t)node * 64 + lane];   // self term: Hs[node] = di*H[node]
    int s0 = rowstart[node], s1 = rowstart[node + 1];
    for (int j = s0; j < s1; j += 8) {
        int srcs[8];
#pragma unroll
        for (int u = 0; u < 8; ++u) srcs[u] = csr[min(j + u, s1 - 1)];
        float2 vs[8];
#pragma unroll
        for (int u = 0; u < 8; ++u) vs[u] = H2[(size_t)srcs[u] * 64 + lane];
#pragma unroll
        for (int u = 0; u < 8; ++u) {
            bool ok = (j + u) < s1;
            acc.x += ok ? vs[u].x : 0.f;
            acc.y += ok ? vs[u].y : 0.f;
        }
    }
    float2 b = reinterpret_cast<const float2*>(bias)[lane];
    float2 o;
    o.x = fmaxf(di * acc.x + b.x, 0.f);
    o.y = fmaxf(di * acc.y + b.y, 0.f);
    reinterpret_cast<float2*>(out)[(size_t)node * 64 + lane] = o;
}

// --- SpMM, F=64: wave per node, lane = float; 8-deep unrolled gather ---------
__global__ __launch_bounds__(256) void k_spmm64(
        const float* __restrict__ Hs, const int* __restrict__ rowstart,
        const int* __restrict__ csr, const float* __restrict__ dinv,
        const float* __restrict__ bias, float* __restrict__ out, int n) {
    int node = blockIdx.x * 4 + (threadIdx.x >> 6);
    if (node >= n) return;
    int lane = threadIdx.x & 63;
    float di = dinv[node];
    float acc = Hs[(size_t)node * 64 + lane];    // self term
    int s0 = rowstart[node], s1 = rowstart[node + 1];
    for (int j = s0; j < s1; j += 8) {
        int srcs[8];
#pragma unroll
        for (int u = 0; u < 8; ++u) srcs[u] = csr[min(j + u, s1 - 1)];
        float vs[8];
#pragma unroll
        for (int u = 0; u < 8; ++u) vs[u] = Hs[(size_t)srcs[u] * 64 + lane];
#pragma unroll
        for (int u = 0; u < 8; ++u) {
            bool ok = (j + u) < s1;
            acc += ok ? vs[u] : 0.f;
        }
    }
    out[(size_t)node * 64 + lane] = di * acc + bias[lane];
}

extern "C" void kernel_launch(void* const* d_in, const int* in_sizes, int n_in,
                              void* d_out, int out_size, void* d_ws, size_t ws_size,
                              hipStream_t stream) {
    const float* X  = (const float*)d_in[0];
    const int*   e32 = (const int*)d_in[1];
    const float* W1 = (const float*)d_in[2];
    const float* b1 = (const float*)d_in[3];
    const float* W2 = (const float*)d_in[4];
    const float* b2 = (const float*)d_in[5];
    float* out = (float*)d_out;

    const int n = in_sizes[0] / 128;
    const int E = in_sizes[1] / 2;

    char* ws = (char*)d_ws;
    int*   deg      = (int*)(ws + WS_OFF_DEG);
    int*   rowstart = (int*)(ws + WS_OFF_ROWSTART);
    int*   cursor   = (int*)(ws + WS_OFF_CURSOR);
    float* dinv     = (float*)(ws + WS_OFF_DINV);
    int*   blocksum = (int*)(ws + WS_OFF_BLOCKSUM);
    int*   flag     = (int*)(ws + WS_OFF_FLAG);
    int*   csr      = (int*)(ws + WS_OFF_CSR);
    float* bufA     = (float*)(ws + WS_OFF_BUFA);   // Hs1 [n][128], later Hs2 [n][64]
    float* bufB     = (float*)(ws + WS_OFF_BUFB);   // X1 [n][128]

    const int NB = (n + 255) / 256;

    k_detect<<<1, 256, 0, stream>>>(e32, flag);
    k_zero_int<<<NB, 256, 0, stream>>>(deg, n);
    k_count<<<(E + 255) / 256, 256, 0, stream>>>(e32, E, flag, deg);
    k_dinv<<<NB, 256, 0, stream>>>(deg, n, dinv);
    k_scan1<<<NB, 256, 0, stream>>>(deg, n, rowstart, blocksum);
    k_scan2<<<1, 256, 0, stream>>>(blocksum, NB);
    k_scan3<<<NB, 256, 0, stream>>>(rowstart, n, blocksum, cursor, E);
    k_fill<<<(E + 255) / 256, 256, 0, stream>>>(e32, E, flag, cursor, csr);

    k_gemm1<<<(n + 127) / 128, 256, 0, stream>>>(X, W1, dinv, bufA, n);
    k_spmm128<<<(n + 3) / 4, 256, 0, stream>>>(bufA, rowstart, csr, dinv, b1, bufB, n);
    k_gemm2<<<(n + 255) / 256, 256, 0, stream>>>(bufB, W2, dinv, bufA, n);
    k_spmm64<<<(n + 3) / 4, 256, 0, stream>>>(bufA, rowstart, csr, dinv, b2, out, n);
}

// Round 3
// 179.555 us; speedup vs baseline: 1.9674x; 1.3987x over previous
//
#include <hip/hip_runtime.h>
#include <hip/hip_bf16.h>

// ---------------------------------------------------------------------------
// 2-layer GCN: out = GCN2( relu(GCN1(X)) ), GCN(x) = Dinv (A+I) Dinv (x W) + b
//   1. zero+detect; count: deg[dst]++ AND rank[e] = old value (atomic ret)
//   2. scan(deg) -> rowstart (+dinv fused); fill: csr[rowstart+rank]=src, NO atomics
//   3. GEMM Hs = (X @ W) * dinv[row], stored BF16 (halves gather traffic)
//   4. SpMM gather: wave(/half-wave)-per-node, 8-deep unrolled MLP,
//      out = dinv[node]*acc + b (+relu) in fp32.
// ---------------------------------------------------------------------------

#define OFF_DEG      (size_t)0          // (n) int
#define OFF_ROWSTART (size_t)200704     // (n+1) int
#define OFF_DINV     (size_t)401408     // n float
#define OFF_BLOCKSUM (size_t)602112     // 256 int
#define OFF_FLAG     (size_t)603136     // 1 int
#define OFF_RANK     (size_t)604160     // E ushort
#define OFF_CSR      (size_t)2204672    // E ushort
#define OFF_BUFA     (size_t)3805184    // bf16 Hs1 [n][128]; later bf16 Hs2 [n][64]
#define OFF_BUFB     (size_t)16605696   // fp32 X1 [n][128]

__device__ __forceinline__ float2 bf2f(unsigned u) {
    float2 r;
    r.x = __uint_as_float(u << 16);
    r.y = __uint_as_float(u & 0xffff0000u);
    return r;
}
__device__ __forceinline__ unsigned f2bf(float a, float b) {
    __hip_bfloat162 h = __float22bfloat162_rn(make_float2(a, b));
    union { __hip_bfloat162 h; unsigned u; } cv;
    cv.h = h;
    return cv.u;
}

// --- zero deg; block 0 also detects edge dtype (flag=1 iff int64) -----------
__global__ void k_zero_detect(int* __restrict__ deg, int n,
                              const int* __restrict__ e32, int* __restrict__ flag) {
    int i = blockIdx.x * 256 + threadIdx.x;
    if (i < n) deg[i] = 0;
    if (blockIdx.x == 0) {
        __shared__ int any;
        if (threadIdx.x == 0) any = 0;
        __syncthreads();
        int v = 0;
        for (int k = threadIdx.x; k < 4096; k += 256) v |= e32[2 * k + 1];
        if (v) atomicOr(&any, 1);
        __syncthreads();
        if (threadIdx.x == 0) *flag = (any == 0) ? 1 : 0;
    }
}

// --- count degree; atomic return value IS the edge's rank within its row ----
__global__ void k_count(const int* __restrict__ e32, int E,
                        const int* __restrict__ flag,
                        int* __restrict__ deg, unsigned short* __restrict__ rank) {
    int e = blockIdx.x * 256 + threadIdx.x;
    if (e >= E) return;
    int f = *flag;                 // uniform
    int dst;
    if (f) dst = reinterpret_cast<const int4*>(e32)[e].z;
    else   dst = reinterpret_cast<const int2*>(e32)[e].y;
    int r = atomicAdd(&deg[dst], 1);
    rank[e] = (unsigned short)r;
}

// --- 3-kernel exclusive scan over deg[n]; scan1 also emits dinv -------------
__global__ void k_scan1(const int* __restrict__ deg, int n,
                        int* __restrict__ rowstart, int* __restrict__ blocksum,
                        float* __restrict__ dinv) {
    __shared__ int sh[256];
    int t = threadIdx.x, i = blockIdx.x * 256 + t;
    int v = (i < n) ? deg[i] : 0;
    if (i < n) dinv[i] = rsqrtf((float)v + 1.0f);
    sh[t] = v;
    __syncthreads();
    for (int off = 1; off < 256; off <<= 1) {
        int add = (t >= off) ? sh[t - off] : 0;
        __syncthreads();
        sh[t] += add;
        __syncthreads();
    }
    if (i < n) rowstart[i] = sh[t] - v;          // block-local exclusive
    if (t == 255) blocksum[blockIdx.x] = sh[255];
}

__global__ void k_scan2(int* __restrict__ blocksum, int nb) {
    __shared__ int sh[256];
    int t = threadIdx.x;
    int v = (t < nb) ? blocksum[t] : 0;
    sh[t] = v;
    __syncthreads();
    for (int off = 1; off < 256; off <<= 1) {
        int add = (t >= off) ? sh[t - off] : 0;
        __syncthreads();
        sh[t] += add;
        __syncthreads();
    }
    if (t < nb) blocksum[t] = sh[t] - v;         // exclusive block offsets
}

__global__ void k_scan3(int* __restrict__ rowstart, int n,
                        const int* __restrict__ blocksum, int E) {
    int i = blockIdx.x * 256 + threadIdx.x;
    if (i < n) rowstart[i] += blocksum[blockIdx.x];
    if (i == 0) rowstart[n] = E;
}

// --- fill CSR: no atomics, position = rowstart[dst] + rank[e] ---------------
__global__ void k_fill(const int* __restrict__ e32, int E,
                       const int* __restrict__ flag,
                       const int* __restrict__ rowstart,
                       const unsigned short* __restrict__ rank,
                       unsigned short* __restrict__ csr) {
    int e = blockIdx.x * 256 + threadIdx.x;
    if (e >= E) return;
    int f = *flag;
    int src, dst;
    if (f) { int4 v = reinterpret_cast<const int4*>(e32)[e]; src = v.x; dst = v.z; }
    else   { int2 v = reinterpret_cast<const int2*>(e32)[e]; src = v.x; dst = v.y; }
    csr[rowstart[dst] + (int)rank[e]] = (unsigned short)src;
}

// --- GEMM1: [n x 128] @ [128 x 128] -> bf16 out scaled by dinv[row] ---------
__global__ __launch_bounds__(256) void k_gemm1(const float* __restrict__ X,
                                               const float* __restrict__ W,
                                               const float* __restrict__ dinv,
                                               __hip_bfloat16* __restrict__ out, int n) {
    __shared__ float XsT[32][132];   // [k][row], padded
    __shared__ float Ws[32][128];    // [k][col]
    const int t = threadIdx.x;
    const int tx = t & 15, ty = t >> 4;
    const int row0 = blockIdx.x * 128;
    float acc[8][8] = {};
    for (int kt = 0; kt < 128; kt += 32) {
        for (int i = t; i < 128 * 8; i += 256) {     // X tile: 128 rows x 8 float4
            int r = i >> 3, c4 = i & 7;
            int gr = row0 + r;
            float4 v = make_float4(0.f, 0.f, 0.f, 0.f);
            if (gr < n) v = reinterpret_cast<const float4*>(X + (size_t)gr * 128 + kt)[c4];
            XsT[c4 * 4 + 0][r] = v.x;
            XsT[c4 * 4 + 1][r] = v.y;
            XsT[c4 * 4 + 2][r] = v.z;
            XsT[c4 * 4 + 3][r] = v.w;
        }
        for (int i = t; i < 32 * 32; i += 256) {     // W tile: 32 rows x 32 float4
            int kk = i >> 5, c4 = i & 31;
            reinterpret_cast<float4*>(&Ws[kk][0])[c4] =
                reinterpret_cast<const float4*>(W + (size_t)(kt + kk) * 128)[c4];
        }
        __syncthreads();
#pragma unroll
        for (int kk = 0; kk < 32; ++kk) {
            float a[8], b[8];
#pragma unroll
            for (int i = 0; i < 8; i++) a[i] = XsT[kk][ty * 8 + i];
#pragma unroll
            for (int j = 0; j < 8; j++) b[j] = Ws[kk][tx * 8 + j];
#pragma unroll
            for (int i = 0; i < 8; i++)
#pragma unroll
                for (int j = 0; j < 8; j++) acc[i][j] += a[i] * b[j];
        }
        __syncthreads();
    }
    for (int i = 0; i < 8; i++) {
        int gr = row0 + ty * 8 + i;
        if (gr < n) {
            float dv = dinv[gr];
            uint4 q;
            q.x = f2bf(acc[i][0] * dv, acc[i][1] * dv);
            q.y = f2bf(acc[i][2] * dv, acc[i][3] * dv);
            q.z = f2bf(acc[i][4] * dv, acc[i][5] * dv);
            q.w = f2bf(acc[i][6] * dv, acc[i][7] * dv);
            *reinterpret_cast<uint4*>(out + (size_t)gr * 128 + tx * 8) = q;
        }
    }
}

// --- GEMM2: [n x 128] @ [128 x 64] -> bf16 out scaled by dinv[row] ----------
__global__ __launch_bounds__(256) void k_gemm2(const float* __restrict__ X,
                                               const float* __restrict__ W,
                                               const float* __restrict__ dinv,
                                               __hip_bfloat16* __restrict__ out, int n) {
    __shared__ float XsT[32][260];   // [k][row], padded
    __shared__ float Ws[32][64];     // [k][col]
    const int t = threadIdx.x;
    const int tx = t & 7, ty = t >> 3;
    const int row0 = blockIdx.x * 256;
    float acc[8][8] = {};
    for (int kt = 0; kt < 128; kt += 32) {
        for (int i = t; i < 256 * 8; i += 256) {     // X tile: 256 rows x 8 float4
            int r = i >> 3, c4 = i & 7;
            int gr = row0 + r;
            float4 v = make_float4(0.f, 0.f, 0.f, 0.f);
            if (gr < n) v = reinterpret_cast<const float4*>(X + (size_t)gr * 128 + kt)[c4];
            XsT[c4 * 4 + 0][r] = v.x;
            XsT[c4 * 4 + 1][r] = v.y;
            XsT[c4 * 4 + 2][r] = v.z;
            XsT[c4 * 4 + 3][r] = v.w;
        }
        for (int i = t; i < 32 * 16; i += 256) {     // W tile: 32 rows x 16 float4
            int kk = i >> 4, c4 = i & 15;
            reinterpret_cast<float4*>(&Ws[kk][0])[c4] =
                reinterpret_cast<const float4*>(W + (size_t)(kt + kk) * 64)[c4];
        }
        __syncthreads();
#pragma unroll
        for (int kk = 0; kk < 32; ++kk) {
            float a[8], b[8];
#pragma unroll
            for (int i = 0; i < 8; i++) a[i] = XsT[kk][ty * 8 + i];
#pragma unroll
            for (int j = 0; j < 8; j++) b[j] = Ws[kk][tx * 8 + j];
#pragma unroll
            for (int i = 0; i < 8; i++)
#pragma unroll
                for (int j = 0; j < 8; j++) acc[i][j] += a[i] * b[j];
        }
        __syncthreads();
    }
    for (int i = 0; i < 8; i++) {
        int gr = row0 + ty * 8 + i;
        if (gr < n) {
            float dv = dinv[gr];
            uint4 q;
            q.x = f2bf(acc[i][0] * dv, acc[i][1] * dv);
            q.y = f2bf(acc[i][2] * dv, acc[i][3] * dv);
            q.z = f2bf(acc[i][4] * dv, acc[i][5] * dv);
            q.w = f2bf(acc[i][6] * dv, acc[i][7] * dv);
            *reinterpret_cast<uint4*>(out + (size_t)gr * 64 + tx * 8) = q;
        }
    }
}

// --- SpMM, F=128: wave per node, lane = bf16x2; 8-deep unrolled gather ------
__global__ __launch_bounds__(256) void k_spmm128(
        const unsigned* __restrict__ H32, const int* __restrict__ rowstart,
        const unsigned short* __restrict__ csr, const float* __restrict__ dinv,
        const float* __restrict__ bias, float* __restrict__ out, int n) {
    int node = blockIdx.x * 4 + (threadIdx.x >> 6);
    if (node >= n) return;
    int lane = threadIdx.x & 63;
    float di = dinv[node];
    float2 acc = bf2f(H32[(size_t)node * 64 + lane]);   // self term (pre-scaled)
    int s0 = rowstart[node], s1 = rowstart[node + 1];
    for (int j = s0; j < s1; j += 8) {
        int srcs[8];
        unsigned uu[8];
#pragma unroll
        for (int u = 0; u < 8; ++u) srcs[u] = csr[min(j + u, s1 - 1)];
#pragma unroll
        for (int u = 0; u < 8; ++u) uu[u] = H32[(size_t)srcs[u] * 64 + lane];
#pragma unroll
        for (int u = 0; u < 8; ++u) {
            float2 fv = bf2f(uu[u]);
            bool ok = (j + u) < s1;
            acc.x += ok ? fv.x : 0.f;
            acc.y += ok ? fv.y : 0.f;
        }
    }
    float2 b = reinterpret_cast<const float2*>(bias)[lane];
    float2 o;
    o.x = fmaxf(fmaf(di, acc.x, b.x), 0.f);
    o.y = fmaxf(fmaf(di, acc.y, b.y), 0.f);
    reinterpret_cast<float2*>(out)[(size_t)node * 64 + lane] = o;
}

// --- SpMM, F=64: HALF-wave per node, lane = bf16x2; 8-deep unrolled ---------
__global__ __launch_bounds__(256) void k_spmm64(
        const unsigned* __restrict__ H32, const int* __restrict__ rowstart,
        const unsigned short* __restrict__ csr, const float* __restrict__ dinv,
        const float* __restrict__ bias, float* __restrict__ out, int n) {
    int node = blockIdx.x * 8 + (threadIdx.x >> 5);
    if (node >= n) return;
    int f2 = threadIdx.x & 31;
    float di = dinv[node];
    float2 acc = bf2f(H32[(size_t)node * 32 + f2]);     // self term
    int s0 = rowstart[node], s1 = rowstart[node + 1];
    for (int j = s0; j < s1; j += 8) {
        int srcs[8];
        unsigned uu[8];
#pragma unroll
        for (int u = 0; u < 8; ++u) srcs[u] = csr[min(j + u, s1 - 1)];
#pragma unroll
        for (int u = 0; u < 8; ++u) uu[u] = H32[(size_t)srcs[u] * 32 + f2];
#pragma unroll
        for (int u = 0; u < 8; ++u) {
            float2 fv = bf2f(uu[u]);
            bool ok = (j + u) < s1;
            acc.x += ok ? fv.x : 0.f;
            acc.y += ok ? fv.y : 0.f;
        }
    }
    float2 b = reinterpret_cast<const float2*>(bias)[f2];
    float2 o;
    o.x = fmaf(di, acc.x, b.x);
    o.y = fmaf(di, acc.y, b.y);
    reinterpret_cast<float2*>(out)[(size_t)node * 32 + f2] = o;
}

extern "C" void kernel_launch(void* const* d_in, const int* in_sizes, int n_in,
                              void* d_out, int out_size, void* d_ws, size_t ws_size,
                              hipStream_t stream) {
    const float* X   = (const float*)d_in[0];
    const int*   e32 = (const int*)d_in[1];
    const float* W1  = (const float*)d_in[2];
    const float* b1  = (const float*)d_in[3];
    const float* W2  = (const float*)d_in[4];
    const float* b2  = (const float*)d_in[5];
    float* out = (float*)d_out;

    const int n = in_sizes[0] / 128;
    const int E = in_sizes[1] / 2;

    char* ws = (char*)d_ws;
    int*            deg      = (int*)(ws + OFF_DEG);
    int*            rowstart = (int*)(ws + OFF_ROWSTART);
    float*          dinv     = (float*)(ws + OFF_DINV);
    int*            blocksum = (int*)(ws + OFF_BLOCKSUM);
    int*            flag     = (int*)(ws + OFF_FLAG);
    unsigned short* rank     = (unsigned short*)(ws + OFF_RANK);
    unsigned short* csr      = (unsigned short*)(ws + OFF_CSR);
    __hip_bfloat16* bufA     = (__hip_bfloat16*)(ws + OFF_BUFA);  // Hs1/Hs2 bf16
    float*          bufB     = (float*)(ws + OFF_BUFB);           // X1 fp32

    const int NB = (n + 255) / 256;
    const int EB = (E + 255) / 256;

    k_zero_detect<<<NB, 256, 0, stream>>>(deg, n, e32, flag);
    k_count<<<EB, 256, 0, stream>>>(e32, E, flag, deg, rank);
    k_scan1<<<NB, 256, 0, stream>>>(deg, n, rowstart, blocksum, dinv);
    k_scan2<<<1, 256, 0, stream>>>(blocksum, NB);
    k_scan3<<<NB, 256, 0, stream>>>(rowstart, n, blocksum, E);
    k_fill<<<EB, 256, 0, stream>>>(e32, E, flag, rowstart, rank, csr);

    k_gemm1<<<(n + 127) / 128, 256, 0, stream>>>(X, W1, dinv, bufA, n);
    k_spmm128<<<(n + 3) / 4, 256, 0, stream>>>((const unsigned*)bufA, rowstart, csr,
                                               dinv, b1, bufB, n);
    k_gemm2<<<(n + 255) / 256, 256, 0, stream>>>(bufB, W2, dinv, bufA, n);
    k_spmm64<<<(n + 7) / 8, 256, 0, stream>>>((const unsigned*)bufA, rowstart, csr,
                                              dinv, b2, out, n);
}

// Round 4
// 165.318 us; speedup vs baseline: 2.1368x; 1.0861x over previous
//
#include <hip/hip_runtime.h>
#include <hip/hip_bf16.h>

// ---------------------------------------------------------------------------
// 2-layer GCN: out = GCN2( relu(GCN1(X)) ), GCN(x) = Dinv (A+I) Dinv (x W) + b
//   1. zero+detect; count: deg[dst]++ AND rank[e] = old value (atomic ret)
//   2. scan(deg) -> rowstart (+dinv fused); fill: csr[rowstart+rank]=src, NO atomics
//   3. GEMM Hs = (X @ W) * dinv[row], stored BF16; 64x64 tiles (occupancy!)
//   4. SpMM gather: wave(/half-wave)-per-node, 8-deep unrolled MLP,
//      out = dinv[node]*acc + b (+relu) in fp32.
// ---------------------------------------------------------------------------

#define OFF_DEG      (size_t)0          // (n) int
#define OFF_ROWSTART (size_t)200704     // (n+1) int
#define OFF_DINV     (size_t)401408     // n float
#define OFF_BLOCKSUM (size_t)602112     // 256 int
#define OFF_FLAG     (size_t)603136     // 1 int
#define OFF_RANK     (size_t)604160     // E ushort
#define OFF_CSR      (size_t)2204672    // E ushort
#define OFF_BUFA     (size_t)3805184    // bf16 Hs1 [n][128]; later bf16 Hs2 [n][64]
#define OFF_BUFB     (size_t)16605696   // fp32 X1 [n][128]

__device__ __forceinline__ float2 bf2f(unsigned u) {
    float2 r;
    r.x = __uint_as_float(u << 16);
    r.y = __uint_as_float(u & 0xffff0000u);
    return r;
}
__device__ __forceinline__ unsigned f2bf(float a, float b) {
    __hip_bfloat162 h = __float22bfloat162_rn(make_float2(a, b));
    union { __hip_bfloat162 h; unsigned u; } cv;
    cv.h = h;
    return cv.u;
}

// --- zero deg; block 0 also detects edge dtype (flag=1 iff int64) -----------
__global__ void k_zero_detect(int* __restrict__ deg, int n,
                              const int* __restrict__ e32, int* __restrict__ flag) {
    int i = blockIdx.x * 256 + threadIdx.x;
    if (i < n) deg[i] = 0;
    if (blockIdx.x == 0) {
        __shared__ int any;
        if (threadIdx.x == 0) any = 0;
        __syncthreads();
        int v = 0;
        for (int k = threadIdx.x; k < 4096; k += 256) v |= e32[2 * k + 1];
        if (v) atomicOr(&any, 1);
        __syncthreads();
        if (threadIdx.x == 0) *flag = (any == 0) ? 1 : 0;
    }
}

// --- count degree; atomic return value IS the edge's rank within its row ----
__global__ void k_count(const int* __restrict__ e32, int E,
                        const int* __restrict__ flag,
                        int* __restrict__ deg, unsigned short* __restrict__ rank) {
    int e = blockIdx.x * 256 + threadIdx.x;
    if (e >= E) return;
    int f = *flag;                 // uniform
    int dst;
    if (f) dst = reinterpret_cast<const int4*>(e32)[e].z;
    else   dst = reinterpret_cast<const int2*>(e32)[e].y;
    int r = atomicAdd(&deg[dst], 1);
    rank[e] = (unsigned short)r;
}

// --- 3-kernel exclusive scan over deg[n]; scan1 also emits dinv -------------
__global__ void k_scan1(const int* __restrict__ deg, int n,
                        int* __restrict__ rowstart, int* __restrict__ blocksum,
                        float* __restrict__ dinv) {
    __shared__ int sh[256];
    int t = threadIdx.x, i = blockIdx.x * 256 + t;
    int v = (i < n) ? deg[i] : 0;
    if (i < n) dinv[i] = rsqrtf((float)v + 1.0f);
    sh[t] = v;
    __syncthreads();
    for (int off = 1; off < 256; off <<= 1) {
        int add = (t >= off) ? sh[t - off] : 0;
        __syncthreads();
        sh[t] += add;
        __syncthreads();
    }
    if (i < n) rowstart[i] = sh[t] - v;          // block-local exclusive
    if (t == 255) blocksum[blockIdx.x] = sh[255];
}

__global__ void k_scan2(int* __restrict__ blocksum, int nb) {
    __shared__ int sh[256];
    int t = threadIdx.x;
    int v = (t < nb) ? blocksum[t] : 0;
    sh[t] = v;
    __syncthreads();
    for (int off = 1; off < 256; off <<= 1) {
        int add = (t >= off) ? sh[t - off] : 0;
        __syncthreads();
        sh[t] += add;
        __syncthreads();
    }
    if (t < nb) blocksum[t] = sh[t] - v;         // exclusive block offsets
}

__global__ void k_scan3(int* __restrict__ rowstart, int n,
                        const int* __restrict__ blocksum, int E) {
    int i = blockIdx.x * 256 + threadIdx.x;
    if (i < n) rowstart[i] += blocksum[blockIdx.x];
    if (i == 0) rowstart[n] = E;
}

// --- fill CSR: no atomics, position = rowstart[dst] + rank[e] ---------------
__global__ void k_fill(const int* __restrict__ e32, int E,
                       const int* __restrict__ flag,
                       const int* __restrict__ rowstart,
                       const unsigned short* __restrict__ rank,
                       unsigned short* __restrict__ csr) {
    int e = blockIdx.x * 256 + threadIdx.x;
    if (e >= E) return;
    int f = *flag;
    int src, dst;
    if (f) { int4 v = reinterpret_cast<const int4*>(e32)[e]; src = v.x; dst = v.z; }
    else   { int2 v = reinterpret_cast<const int2*>(e32)[e]; src = v.x; dst = v.y; }
    csr[rowstart[dst] + (int)rank[e]] = (unsigned short)src;
}

// --- GEMM: [n x 128] @ [128 x ncol] -> bf16 out scaled by dinv[row] ---------
// 64x64 output tile per block; grid = (ceil(n/64), ncol/64). micro 4x4.
__global__ __launch_bounds__(256) void k_gemm64(const float* __restrict__ X,
                                                const float* __restrict__ W,
                                                const float* __restrict__ dinv,
                                                __hip_bfloat16* __restrict__ out,
                                                int n, int ncol) {
    __shared__ float XsT[32][68];    // [k][row], padded (272B row, 16B-aligned)
    __shared__ float Ws[32][68];     // [k][col], padded
    const int t = threadIdx.x;
    const int tx = t & 15, ty = t >> 4;
    const int row0 = blockIdx.x * 64;
    const int col0 = blockIdx.y * 64;
    float acc[4][4] = {};
    for (int kt = 0; kt < 128; kt += 32) {
#pragma unroll
        for (int it = 0; it < 2; ++it) {            // X tile: 64 rows x 8 float4
            int i = t + it * 256;
            int r = i >> 3, c4 = i & 7;
            int gr = row0 + r;
            float4 v = make_float4(0.f, 0.f, 0.f, 0.f);
            if (gr < n) v = *reinterpret_cast<const float4*>(X + (size_t)gr * 128 + kt + c4 * 4);
            XsT[c4 * 4 + 0][r] = v.x;
            XsT[c4 * 4 + 1][r] = v.y;
            XsT[c4 * 4 + 2][r] = v.z;
            XsT[c4 * 4 + 3][r] = v.w;
        }
#pragma unroll
        for (int it = 0; it < 2; ++it) {            // W tile: 32 k x 16 float4
            int i = t + it * 256;
            int kk = i >> 4, c4 = i & 15;
            *reinterpret_cast<float4*>(&Ws[kk][c4 * 4]) =
                *reinterpret_cast<const float4*>(W + (size_t)(kt + kk) * ncol + col0 + c4 * 4);
        }
        __syncthreads();
#pragma unroll
        for (int kk = 0; kk < 32; ++kk) {
            float4 a = *reinterpret_cast<const float4*>(&XsT[kk][ty * 4]);
            float4 b = *reinterpret_cast<const float4*>(&Ws[kk][tx * 4]);
            float av[4] = {a.x, a.y, a.z, a.w};
            float bv[4] = {b.x, b.y, b.z, b.w};
#pragma unroll
            for (int i = 0; i < 4; i++)
#pragma unroll
                for (int j = 0; j < 4; j++) acc[i][j] += av[i] * bv[j];
        }
        __syncthreads();
    }
#pragma unroll
    for (int i = 0; i < 4; i++) {
        int gr = row0 + ty * 4 + i;
        if (gr < n) {
            float dv = dinv[gr];
            uint2 q;
            q.x = f2bf(acc[i][0] * dv, acc[i][1] * dv);
            q.y = f2bf(acc[i][2] * dv, acc[i][3] * dv);
            *reinterpret_cast<uint2*>(out + (size_t)gr * ncol + col0 + tx * 4) = q;
        }
    }
}

// --- SpMM, F=128: wave per node, lane = bf16x2; 8-deep unrolled gather ------
__global__ __launch_bounds__(256) void k_spmm128(
        const unsigned* __restrict__ H32, const int* __restrict__ rowstart,
        const unsigned short* __restrict__ csr, const float* __restrict__ dinv,
        const float* __restrict__ bias, float* __restrict__ out, int n) {
    int node = blockIdx.x * 4 + (threadIdx.x >> 6);
    if (node >= n) return;
    int lane = threadIdx.x & 63;
    float di = dinv[node];
    float2 acc = bf2f(H32[(size_t)node * 64 + lane]);   // self term (pre-scaled)
    int s0 = rowstart[node], s1 = rowstart[node + 1];
    for (int j = s0; j < s1; j += 8) {
        int srcs[8];
        unsigned uu[8];
#pragma unroll
        for (int u = 0; u < 8; ++u) srcs[u] = csr[min(j + u, s1 - 1)];
#pragma unroll
        for (int u = 0; u < 8; ++u) uu[u] = H32[(size_t)srcs[u] * 64 + lane];
#pragma unroll
        for (int u = 0; u < 8; ++u) {
            float2 fv = bf2f(uu[u]);
            bool ok = (j + u) < s1;
            acc.x += ok ? fv.x : 0.f;
            acc.y += ok ? fv.y : 0.f;
        }
    }
    float2 b = reinterpret_cast<const float2*>(bias)[lane];
    float2 o;
    o.x = fmaxf(fmaf(di, acc.x, b.x), 0.f);
    o.y = fmaxf(fmaf(di, acc.y, b.y), 0.f);
    reinterpret_cast<float2*>(out)[(size_t)node * 64 + lane] = o;
}

// --- SpMM, F=64: HALF-wave per node, lane = bf16x2; 8-deep unrolled ---------
__global__ __launch_bounds__(256) void k_spmm64(
        const unsigned* __restrict__ H32, const int* __restrict__ rowstart,
        const unsigned short* __restrict__ csr, const float* __restrict__ dinv,
        const float* __restrict__ bias, float* __restrict__ out, int n) {
    int node = blockIdx.x * 8 + (threadIdx.x >> 5);
    if (node >= n) return;
    int f2 = threadIdx.x & 31;
    float di = dinv[node];
    float2 acc = bf2f(H32[(size_t)node * 32 + f2]);     // self term
    int s0 = rowstart[node], s1 = rowstart[node + 1];
    for (int j = s0; j < s1; j += 8) {
        int srcs[8];
        unsigned uu[8];
#pragma unroll
        for (int u = 0; u < 8; ++u) srcs[u] = csr[min(j + u, s1 - 1)];
#pragma unroll
        for (int u = 0; u < 8; ++u) uu[u] = H32[(size_t)srcs[u] * 32 + f2];
#pragma unroll
        for (int u = 0; u < 8; ++u) {
            float2 fv = bf2f(uu[u]);
            bool ok = (j + u) < s1;
            acc.x += ok ? fv.x : 0.f;
            acc.y += ok ? fv.y : 0.f;
        }
    }
    float2 b = reinterpret_cast<const float2*>(bias)[f2];
    float2 o;
    o.x = fmaf(di, acc.x, b.x);
    o.y = fmaf(di, acc.y, b.y);
    reinterpret_cast<float2*>(out)[(size_t)node * 32 + f2] = o;
}

extern "C" void kernel_launch(void* const* d_in, const int* in_sizes, int n_in,
                              void* d_out, int out_size, void* d_ws, size_t ws_size,
                              hipStream_t stream) {
    const float* X   = (const float*)d_in[0];
    const int*   e32 = (const int*)d_in[1];
    const float* W1  = (const float*)d_in[2];
    const float* b1  = (const float*)d_in[3];
    const float* W2  = (const float*)d_in[4];
    const float* b2  = (const float*)d_in[5];
    float* out = (float*)d_out;

    const int n = in_sizes[0] / 128;
    const int E = in_sizes[1] / 2;

    char* ws = (char*)d_ws;
    int*            deg      = (int*)(ws + OFF_DEG);
    int*            rowstart = (int*)(ws + OFF_ROWSTART);
    float*          dinv     = (float*)(ws + OFF_DINV);
    int*            blocksum = (int*)(ws + OFF_BLOCKSUM);
    int*            flag     = (int*)(ws + OFF_FLAG);
    unsigned short* rank     = (unsigned short*)(ws + OFF_RANK);
    unsigned short* csr      = (unsigned short*)(ws + OFF_CSR);
    __hip_bfloat16* bufA     = (__hip_bfloat16*)(ws + OFF_BUFA);  // Hs1/Hs2 bf16
    float*          bufB     = (float*)(ws + OFF_BUFB);           // X1 fp32

    const int NB = (n + 255) / 256;
    const int EB = (E + 255) / 256;
    const int RB = (n + 63) / 64;

    k_zero_detect<<<NB, 256, 0, stream>>>(deg, n, e32, flag);
    k_count<<<EB, 256, 0, stream>>>(e32, E, flag, deg, rank);
    k_scan1<<<NB, 256, 0, stream>>>(deg, n, rowstart, blocksum, dinv);
    k_scan2<<<1, 256, 0, stream>>>(blocksum, NB);
    k_scan3<<<NB, 256, 0, stream>>>(rowstart, n, blocksum, E);
    k_fill<<<EB, 256, 0, stream>>>(e32, E, flag, rowstart, rank, csr);

    k_gemm64<<<dim3(RB, 2), 256, 0, stream>>>(X, W1, dinv, bufA, n, 128);
    k_spmm128<<<(n + 3) / 4, 256, 0, stream>>>((const unsigned*)bufA, rowstart, csr,
                                               dinv, b1, bufB, n);
    k_gemm64<<<dim3(RB, 1), 256, 0, stream>>>(bufB, W2, dinv, bufA, n, 64);
    k_spmm64<<<(n + 7) / 8, 256, 0, stream>>>((const unsigned*)bufA, rowstart, csr,
                                              dinv, b2, out, n);
}